// Round 4
// baseline (479.454 us; speedup 1.0000x reference)
//
#include <hip/hip_runtime.h>

typedef unsigned long long u64;
typedef unsigned int u32;

#define N0 147456   // 384*384
#define N1 36864    // 192*192
#define NTOT 184320 // = 720 * 256 exactly
#define NBLK 720
#define KKP 512
#define KM 128
#define NBINS 16384
#define CAP_COL 2048

struct InPtrs {
  const float* rep[2][2];   // [img][level]
  const float* rel[2][2];
  const float* desc[2][2];
};

// ---------------- candidate generation ----------------
// slot = img*2 + b. Key = (score_bits<<32) | ~pixel_index  ->  descending sort
// == descending score, ties broken by LOWER index (matches lax.top_k).
// Block-DETERMINISTIC output: block blk writes its survivors (compacted via
// LDS) at cand[slot][blk*256 ...] and bcnt[slot][blk] unconditionally.
// No global atomics, no pre-zeroed counters -> the ws memset dispatch is gone.
__global__ __launch_bounds__(256) void cand_kernel(InPtrs P, u64* __restrict__ cand,
                                                   int* __restrict__ bcnt) {
  __shared__ u64 buf[256];
  __shared__ int lcnt;
  int slot = blockIdx.y;
  int img = slot >> 1, b = slot & 1;
  int p = blockIdx.x * 256 + threadIdx.x;   // NTOT == 720*256, no tail
  if (threadIdx.x == 0) lcnt = 0;
  __syncthreads();
  int level, W, q, Npix;
  if (p < N0) { level = 0; W = 384; q = p; Npix = N0; }
  else        { level = 1; W = 192; q = p - N0; Npix = N1; }
  const float* rp = P.rep[img][level] + (size_t)b * Npix;
  const float* rl = P.rel[img][level] + (size_t)b * Npix;
  float v = rp[q];
  float m = sqrtf(v * rl[q]);
  bool ok = (m >= 0.7f);
  if (ok) {
    int y = q / W, x = q - y * W;   // square levels: H == W
    int y0 = (y > 0) ? y - 1 : y, y1 = (y < W - 1) ? y + 1 : y;
    int x0 = (x > 0) ? x - 1 : x, x1 = (x < W - 1) ? x + 1 : x;
    for (int yy = y0; yy <= y1 && ok; ++yy)
      for (int xx = x0; xx <= x1; ++xx)
        if (rp[yy * W + xx] > v) { ok = false; break; }
  }
  if (ok) {
    u32 sb = __float_as_uint(m);
    int pos = atomicAdd(&lcnt, 1);          // LDS atomic only
    buf[pos] = ((u64)sb << 32) | (u32)(~(u32)p);
  }
  __syncthreads();
  int n = lcnt;
  if ((int)threadIdx.x < n)
    cand[(size_t)slot * NTOT + blockIdx.x * 256 + threadIdx.x] = buf[threadIdx.x];
  if (threadIdx.x == 0) bcnt[slot * NBLK + blockIdx.x] = n;
}

// ---------------- dynamic-size bitonic sort (P2 = pow2 <= 2048), descending ----------
__device__ inline void bitonic_dyn(u64* k, int t, int P2) {
  for (int size = 2; size <= P2; size <<= 1) {
    for (int j = size >> 1; j > 0; j >>= 1) {
      __syncthreads();
      for (int i = t; i < P2; i += 1024) {
        int ixj = i ^ j;
        if (ixj > i) {
          u64 a = k[i], b = k[ixj];
          bool desc = ((i & size) == 0);
          if (desc ? (a < b) : (a > b)) { k[i] = b; k[ixj] = a; }
        }
      }
    }
  }
  __syncthreads();
}

// ---------------- keypoint top-512: radix-select + exact sort + decode ----------------
// hist bin = (key >> 41) & 16383 = top-14 mantissa bits; all scores in [0.7,1)
// (exponent 126) so the bin is monotone in score. Reads block sublists (threads
// 0..719 each own one block's compacted list; avg ~13, max 256 entries).
__global__ __launch_bounds__(1024) void kp_select(const u64* __restrict__ cand,
                                                  const int* __restrict__ bcnt,
                                                  float* __restrict__ kp_loc,
                                                  int* __restrict__ kp_level,
                                                  int* __restrict__ kp_p,
                                                  float* __restrict__ kp_score) {
  __shared__ int hist[NBINS];
  __shared__ u64 kbuf[CAP_COL];
  __shared__ int part[1024];
  __shared__ int Bbin, colcnt;
  int slot = blockIdx.x;
  int t = threadIdx.x;
  const u64* keys = cand + (size_t)slot * NTOT;
  for (int i = t; i < NBINS; i += 1024) hist[i] = 0;
  if (t == 0) { Bbin = 0; colcnt = 0; }
  __syncthreads();
  int myn = (t < NBLK) ? bcnt[slot * NBLK + t] : 0;
  const u64* mysub = keys + t * 256;
  for (int i = 0; i < myn; ++i) {
    u32 bin = (u32)((mysub[i] >> 41) & (NBINS - 1));
    atomicAdd(&hist[bin], 1);
  }
  __syncthreads();
  const int BPT = NBINS / 1024;
  int base = t * BPT;
  int lsum = 0;
  for (int j = 0; j < BPT; ++j) lsum += hist[base + j];
  part[t] = lsum;
  __syncthreads();
  for (int off = 1; off < 1024; off <<= 1) {   // suffix scan
    int v = (t + off < 1024) ? part[t + off] : 0;
    __syncthreads();
    part[t] += v;
    __syncthreads();
  }
  int Sab = part[t] - lsum;   // count strictly above my bin range
  if (Sab < KKP && Sab + lsum >= KKP) {
    int c = Sab;
    for (int j = BPT - 1; j >= 0; --j) {
      c += hist[base + j];
      if (c >= KKP) { Bbin = base + j; break; }
    }
  }
  __syncthreads();
  int Bb = Bbin;
  for (int i = 0; i < myn; ++i) {
    u64 kk = mysub[i];
    if ((int)((kk >> 41) & (NBINS - 1)) >= Bb) {
      int pos = atomicAdd(&colcnt, 1);
      if (pos < CAP_COL) kbuf[pos] = kk;
    }
  }
  __syncthreads();
  int nc = colcnt; if (nc > CAP_COL) nc = CAP_COL;
  int P2 = KKP; while (P2 < nc) P2 <<= 1;     // typically 512 or 1024
  for (int i = t; i < P2; i += 1024) if (i >= nc) kbuf[i] = 0;
  __syncthreads();
  bitonic_dyn(kbuf, t, P2);
  // fused decode (t < 512)
  if (t < KKP) {
    u64 key = kbuf[t];
    float s = __uint_as_float((u32)(key >> 32));
    u32 idx = ~(u32)key;
    int level, p, W, scale;
    if (idx < N0) { level = 0; p = (int)idx; W = 384; scale = 1; }
    else          { level = 1; p = (int)(idx - N0); W = 192; scale = 2; }
    if (p < 0 || p >= (level ? N1 : N0)) { p = 0; s = 0.f; }  // pad guard
    int y = p / W, x = p - y * W;
    kp_loc[(slot * 2 + 0) * KKP + t] = (float)(y * scale);
    kp_loc[(slot * 2 + 1) * KKP + t] = (float)(x * scale);
    kp_level[slot * KKP + t] = level;
    kp_p[slot * KKP + t] = p;
    kp_score[slot * KKP + t] = s;
  }
}

// ---------------- gather descriptors * score (TRANSPOSED out: dAt[slot][c][k]) ----------
__global__ __launch_bounds__(512) void gather_kernel(InPtrs P, const int* __restrict__ kp_level,
                                                     const int* __restrict__ kp_p,
                                                     const float* __restrict__ kp_score,
                                                     float* __restrict__ dAt) {
  int slot = blockIdx.y;
  int c = blockIdx.x;       // 0..127 channel
  int k = threadIdx.x;      // 0..511 keypoint
  int img = slot >> 1, b = slot & 1;
  int level = kp_level[slot * KKP + k];
  int p = kp_p[slot * KKP + k];
  float s = kp_score[slot * KKP + k];
  const float* dptr = P.desc[img][level];
  size_t HW = level ? N1 : N0;
  float v = dptr[((size_t)b * 128 + c) * HW + p];
  dAt[((size_t)slot * 128 + c) * KKP + k] = v * s;
}

// ---------------- fp32 GEMM: S[b][k][l] = sum_c A_t[c][k]*B_t[c][l] ----------------
// 64x64 tile / block(16x16), 4x4 acc per thread, float4 LDS fragments.
__global__ __launch_bounds__(256) void gemm_kernel(const float* __restrict__ dAt,
                                                   float* __restrict__ S) {
  __shared__ float tA[128][68];   // [c][row], 68 = 64 + 4 pad
  __shared__ float tB[128][68];
  int b = blockIdx.z;
  const float* A  = dAt + (size_t)b * 128 * KKP;        // slot img0 = b
  const float* Bm = dAt + (size_t)(2 + b) * 128 * KKP;  // slot img1 = 2+b
  int row0 = blockIdx.y * 64, col0 = blockIdx.x * 64;
  int t = threadIdx.y * 16 + threadIdx.x;
  for (int i = t; i < 2048; i += 256) {                 // 128c x 16 float4
    int c = i >> 4, r4 = (i & 15) << 2;
    *(float4*)&tA[c][r4] = *(const float4*)&A[c * KKP + row0 + r4];
    *(float4*)&tB[c][r4] = *(const float4*)&Bm[c * KKP + col0 + r4];
  }
  __syncthreads();
  float acc[4][4] = {};
  int ra = threadIdx.y * 4, rb = threadIdx.x * 4;
  for (int k = 0; k < 128; ++k) {
    float4 a4 = *(const float4*)&tA[k][ra];
    float4 b4 = *(const float4*)&tB[k][rb];
    float a[4] = {a4.x, a4.y, a4.z, a4.w};
    float bb[4] = {b4.x, b4.y, b4.z, b4.w};
    for (int i = 0; i < 4; ++i)
      for (int j = 0; j < 4; ++j)
        acc[i][j] += a[i] * bb[j];
  }
  for (int i = 0; i < 4; ++i) {
    float4 v = {acc[i][0], acc[i][1], acc[i][2], acc[i][3]};
    *(float4*)&S[(size_t)b * KKP * KKP + (size_t)(row0 + ra + i) * KKP + (col0 + rb)] = v;
  }
}

// ---------------- match finalize: hist + scan + collect + sort + output ----------------
// One block per batch. Pass 1: LDS histogram of fkey32(S) (bin = key>>18).
// Suffix-scan -> threshold bin. Pass 2 (L2-hot): collect survivors, dynamic
// bitonic sort (typically 256 elems), decode top-128, write out.
__device__ inline u32 fkey32(float v) {
  u32 bits = __float_as_uint(v);
  return (bits & 0x80000000u) ? ~bits : (bits | 0x80000000u);
}

__global__ __launch_bounds__(1024) void match_finalize(const float* __restrict__ S,
                                                       const float* __restrict__ kp_loc,
                                                       float* __restrict__ out) {
  __shared__ int hist[NBINS];
  __shared__ u64 kbuf[CAP_COL];
  __shared__ int part[1024];
  __shared__ int Bbin, colcnt;
  int b = blockIdx.x;
  int t = threadIdx.x;
  const float* Sb = S + (size_t)b * KKP * KKP;
  for (int i = t; i < NBINS; i += 1024) hist[i] = 0;
  if (t == 0) { Bbin = 0; colcnt = 0; }
  __syncthreads();
  for (int i = t; i < KKP * KKP; i += 1024)          // 256 coalesced iters
    atomicAdd(&hist[fkey32(Sb[i]) >> 18], 1);
  __syncthreads();
  const int BPT = NBINS / 1024;
  int base = t * BPT;
  int lsum = 0;
  for (int j = 0; j < BPT; ++j) lsum += hist[base + j];
  part[t] = lsum;
  __syncthreads();
  for (int off = 1; off < 1024; off <<= 1) {   // suffix scan
    int v = (t + off < 1024) ? part[t + off] : 0;
    __syncthreads();
    part[t] += v;
    __syncthreads();
  }
  int Sab = part[t] - lsum;
  if (Sab < KM && Sab + lsum >= KM) {
    int c = Sab;
    for (int j = BPT - 1; j >= 0; --j) {
      c += hist[base + j];
      if (c >= KM) { Bbin = base + j; break; }
    }
  }
  __syncthreads();
  int Bb = Bbin;
  for (int i = t; i < KKP * KKP; i += 1024) {
    u32 key32 = fkey32(Sb[i]);
    if ((int)(key32 >> 18) >= Bb) {
      int pos = atomicAdd(&colcnt, 1);
      if (pos < CAP_COL) kbuf[pos] = ((u64)key32 << 32) | (u32)(~(u32)i);
    }
  }
  __syncthreads();
  int nc = colcnt; if (nc > CAP_COL) nc = CAP_COL;
  int P2 = KM; while (P2 < nc) P2 <<= 1;      // typically 256
  for (int i = t; i < P2; i += 1024) if (i >= nc) kbuf[i] = 0;
  __syncthreads();
  bitonic_dyn(kbuf, t, P2);
  if (t < KM) {
    u64 key = kbuf[t];
    u32 flat = ~(u32)key;
    int i1 = (int)(flat >> 9), i2 = (int)(flat & 511);
    if (i1 >= KKP) { i1 = 0; i2 = 0; }  // pad guard (never hit: 262144 finite scores)
    int slot1 = b, slot2 = 2 + b;
    out[(b * 4 + 0) * KM + t] = kp_loc[(slot1 * 2 + 0) * KKP + i1];
    out[(b * 4 + 1) * KM + t] = kp_loc[(slot1 * 2 + 1) * KKP + i1];
    out[(b * 4 + 2) * KM + t] = kp_loc[(slot2 * 2 + 0) * KKP + i2];
    out[(b * 4 + 3) * KM + t] = kp_loc[(slot2 * 2 + 1) * KKP + i2];
  }
}

extern "C" void kernel_launch(void* const* d_in, const int* in_sizes, int n_in,
                              void* d_out, int out_size, void* d_ws, size_t ws_size,
                              hipStream_t stream) {
  (void)in_sizes; (void)n_in; (void)out_size; (void)ws_size;
  InPtrs P;
  P.rep[0][0] = (const float*)d_in[0];  P.rel[0][0] = (const float*)d_in[1];  P.desc[0][0] = (const float*)d_in[2];
  P.rep[0][1] = (const float*)d_in[3];  P.rel[0][1] = (const float*)d_in[4];  P.desc[0][1] = (const float*)d_in[5];
  P.rep[1][0] = (const float*)d_in[6];  P.rel[1][0] = (const float*)d_in[7];  P.desc[1][0] = (const float*)d_in[8];
  P.rep[1][1] = (const float*)d_in[9];  P.rel[1][1] = (const float*)d_in[10]; P.desc[1][1] = (const float*)d_in[11];

  char* ws = (char*)d_ws;
  int*   bcnt    = (int*)(ws + 0);                         // 4*720 ints, written unconditionally
  size_t off = 16384;
  u64*   cand    = (u64*)(ws + off);  off += 4ULL * NTOT * 8;      // 5.9 MB, block-deterministic
  float* kp_loc  = (float*)(ws + off); off += 4ULL * 2 * KKP * 4;
  int*   kp_level= (int*)(ws + off);  off += 4ULL * KKP * 4;
  int*   kp_p    = (int*)(ws + off);  off += 4ULL * KKP * 4;
  float* kp_score= (float*)(ws + off); off += 4ULL * KKP * 4;
  float* dAt     = (float*)(ws + off); off += 4ULL * KKP * 128 * 4;
  float* S       = (float*)(ws + off); off += 2ULL * KKP * KKP * 4;

  // 5 dispatches, no memset, no global atomics anywhere.
  cand_kernel<<<dim3(NBLK, 4), 256, 0, stream>>>(P, cand, bcnt);
  kp_select<<<4, 1024, 0, stream>>>(cand, bcnt, kp_loc, kp_level, kp_p, kp_score);
  gather_kernel<<<dim3(128, 4), 512, 0, stream>>>(P, kp_level, kp_p, kp_score, dAt);
  gemm_kernel<<<dim3(8, 8, 2), dim3(16, 16), 0, stream>>>(dAt, S);
  match_finalize<<<2, 1024, 0, stream>>>(S, kp_loc, (float*)d_out);
}